// Round 1
// baseline (5953.564 us; speedup 1.0000x reference)
//
#include <hip/hip_runtime.h>

#define N_NODES 50000
#define E_EDGES 800000
#define DIM_IN 256
#define DIM_H 256
#define DIM_OUT 64
#define SLOPE 0.01f

// ---------------- degree / normalization ----------------

__global__ void init_deg_kernel(float* __restrict__ deg) {
    int i = blockIdx.x * blockDim.x + threadIdx.x;
    if (i < N_NODES) deg[i] = 1.0f;   // self loop
}

__global__ void count_deg_kernel(const int* __restrict__ dst, float* __restrict__ deg) {
    int e = blockIdx.x * blockDim.x + threadIdx.x;
    if (e < E_EDGES) atomicAdd(&deg[dst[e]], 1.0f);
}

__global__ void deg_to_dinv_kernel(float* __restrict__ deg) {
    int i = blockIdx.x * blockDim.x + threadIdx.x;
    if (i < N_NODES) deg[i] = rsqrtf(deg[i]);   // deg >= 1 always (self loops)
}

// ---------------- GEMM: C[M,Nc] = A[M,K] * B[Nc,K]^T (both row-major) ----------------
// BM=64, BN=64, BK=32, 256 threads, 4x4 micro-tile per thread.

__global__ __launch_bounds__(256) void gemm_nt_kernel(
        const float* __restrict__ A, const float* __restrict__ B,
        float* __restrict__ C, int M, int Nc, int K) {
    const int BM = 64, BN = 64, BK = 32;
    __shared__ float As[BK][BM + 4];   // [k][m], +4 pad keeps 16B alignment & breaks conflicts
    __shared__ float Bs[BK][BN + 4];   // [k][n]

    int bm = blockIdx.x * BM;
    int bn = blockIdx.y * BN;
    int tid = threadIdx.x;
    int tm = (tid >> 4) * 4;   // 0..60
    int tn = (tid & 15) * 4;   // 0..60

    float acc[4][4] = {};

    for (int k0 = 0; k0 < K; k0 += BK) {
        // Load A tile: 64 rows x 32 cols = 512 float4, 2 per thread
        #pragma unroll
        for (int p = 0; p < 2; ++p) {
            int idx = p * 256 + tid;
            int row = idx >> 3;          // 0..63
            int col = (idx & 7) << 2;    // 0,4,...,28
            int gr = bm + row;
            float4 v = make_float4(0.f, 0.f, 0.f, 0.f);
            if (gr < M) v = *(const float4*)(A + (size_t)gr * K + k0 + col);
            As[col + 0][row] = v.x; As[col + 1][row] = v.y;
            As[col + 2][row] = v.z; As[col + 3][row] = v.w;
        }
        // Load B tile (Nc is a multiple of 64, K multiple of 32 -> no guards)
        #pragma unroll
        for (int p = 0; p < 2; ++p) {
            int idx = p * 256 + tid;
            int row = idx >> 3;
            int col = (idx & 7) << 2;
            float4 v = *(const float4*)(B + (size_t)(bn + row) * K + k0 + col);
            Bs[col + 0][row] = v.x; Bs[col + 1][row] = v.y;
            Bs[col + 2][row] = v.z; Bs[col + 3][row] = v.w;
        }
        __syncthreads();

        #pragma unroll
        for (int k = 0; k < BK; ++k) {
            float a[4], b[4];
            #pragma unroll
            for (int i = 0; i < 4; ++i) a[i] = As[k][tm + i];
            #pragma unroll
            for (int j = 0; j < 4; ++j) b[j] = Bs[k][tn + j];
            #pragma unroll
            for (int i = 0; i < 4; ++i)
                #pragma unroll
                for (int j = 0; j < 4; ++j)
                    acc[i][j] = fmaf(a[i], b[j], acc[i][j]);
        }
        __syncthreads();
    }

    #pragma unroll
    for (int i = 0; i < 4; ++i) {
        int row = bm + tm + i;
        if (row < M) {
            float4 v = make_float4(acc[i][0], acc[i][1], acc[i][2], acc[i][3]);
            *(float4*)(C + (size_t)row * Nc + bn + tn) = v;
        }
    }
}

// ---------------- self-loop init: out[i,:] = h[i,:] * dinv[i]^2 ----------------

template<int D>
__global__ void init_self_kernel(const float* __restrict__ h, const float* __restrict__ dinv,
                                 float* __restrict__ out) {
    size_t idx = (size_t)blockIdx.x * blockDim.x + threadIdx.x;   // float4 index
    size_t total = (size_t)N_NODES * D / 4;
    if (idx >= total) return;
    int node = (int)(idx / (D / 4));
    float n = dinv[node];
    n = n * n;
    float4 v = ((const float4*)h)[idx];
    v.x *= n; v.y *= n; v.z *= n; v.w *= n;
    ((float4*)out)[idx] = v;
}

// ---------------- edge aggregation: out[dst] += h[src] * dinv[src]*dinv[dst] ----------------
// One 64-lane wave per edge.

template<int D>
__global__ void aggregate_edges_kernel(const int* __restrict__ src, const int* __restrict__ dst,
                                       const float* __restrict__ dinv, const float* __restrict__ h,
                                       float* __restrict__ out) {
    size_t gtid = (size_t)blockIdx.x * blockDim.x + threadIdx.x;
    int edge = (int)(gtid >> 6);
    int lane = (int)(gtid & 63);
    if (edge >= E_EDGES) return;
    int s = src[edge];
    int d = dst[edge];
    float norm = dinv[s] * dinv[d];
    if (D == 256) {
        float4 v = *((const float4*)(h + (size_t)s * 256) + lane);
        float* op = out + (size_t)d * 256 + (size_t)lane * 4;
        atomicAdd(op + 0, v.x * norm);
        atomicAdd(op + 1, v.y * norm);
        atomicAdd(op + 2, v.z * norm);
        atomicAdd(op + 3, v.w * norm);
    } else {   // D == 64
        float v = h[(size_t)s * 64 + lane];
        atomicAdd(out + (size_t)d * 64 + lane, v * norm);
    }
}

// ---------------- bias + optional leaky-relu, in place ----------------

template<int D, bool ACT>
__global__ void bias_act_kernel(float* __restrict__ out, const float* __restrict__ b) {
    size_t idx = (size_t)blockIdx.x * blockDim.x + threadIdx.x;   // float4 index
    size_t total = (size_t)N_NODES * D / 4;
    if (idx >= total) return;
    int col4 = (int)(idx % (D / 4)) * 4;
    float4 v = ((const float4*)out)[idx];
    v.x += b[col4 + 0]; v.y += b[col4 + 1]; v.z += b[col4 + 2]; v.w += b[col4 + 3];
    if (ACT) {
        v.x = v.x > 0.f ? v.x : SLOPE * v.x;
        v.y = v.y > 0.f ? v.y : SLOPE * v.y;
        v.z = v.z > 0.f ? v.z : SLOPE * v.z;
        v.w = v.w > 0.f ? v.w : SLOPE * v.w;
    }
    ((float4*)out)[idx] = v;
}

// ---------------- launch ----------------

static inline int cdiv(long long a, long long b) { return (int)((a + b - 1) / b); }

extern "C" void kernel_launch(void* const* d_in, const int* in_sizes, int n_in,
                              void* d_out, int out_size, void* d_ws, size_t ws_size,
                              hipStream_t stream) {
    const float* x  = (const float*)d_in[0];
    const int* ei   = (const int*)d_in[1];
    const float* W1 = (const float*)d_in[2];
    const float* b1 = (const float*)d_in[3];
    const float* W2 = (const float*)d_in[4];
    const float* b2 = (const float*)d_in[5];
    const float* W3 = (const float*)d_in[6];
    const float* b3 = (const float*)d_in[7];

    const int* src = ei;             // edge_index[0]
    const int* dst = ei + E_EDGES;   // edge_index[1]

    float* dinv = (float*)d_ws;                       // N floats (deg -> dinv in place)
    float* h    = (float*)d_ws + 65536;               // N * 256 floats scratch

    float* out1 = (float*)d_out;                              // [N, 256]
    float* out2 = out1 + (size_t)N_NODES * DIM_H;             // [N, 256]
    float* out3 = out2 + (size_t)N_NODES * DIM_H;             // [N, 64]

    // normalization (shared by all layers)
    init_deg_kernel<<<cdiv(N_NODES, 256), 256, 0, stream>>>(dinv);
    count_deg_kernel<<<cdiv(E_EDGES, 256), 256, 0, stream>>>(dst, dinv);
    deg_to_dinv_kernel<<<cdiv(N_NODES, 256), 256, 0, stream>>>(dinv);

    dim3 gemm_grid_h(cdiv(N_NODES, 64), DIM_H / 64);
    dim3 gemm_grid_o(cdiv(N_NODES, 64), DIM_OUT / 64);
    int ew_grid_256 = cdiv((long long)N_NODES * 256 / 4, 256);
    int ew_grid_64  = cdiv((long long)N_NODES * 64 / 4, 256);
    int agg_grid    = cdiv((long long)E_EDGES * 64, 256);

    // ---- layer 1 ----
    gemm_nt_kernel<<<gemm_grid_h, 256, 0, stream>>>(x, W1, h, N_NODES, DIM_H, DIM_IN);
    init_self_kernel<256><<<ew_grid_256, 256, 0, stream>>>(h, dinv, out1);
    aggregate_edges_kernel<256><<<agg_grid, 256, 0, stream>>>(src, dst, dinv, h, out1);
    bias_act_kernel<256, true><<<ew_grid_256, 256, 0, stream>>>(out1, b1);

    // ---- layer 2 ----
    gemm_nt_kernel<<<gemm_grid_h, 256, 0, stream>>>(out1, W2, h, N_NODES, DIM_H, DIM_H);
    init_self_kernel<256><<<ew_grid_256, 256, 0, stream>>>(h, dinv, out2);
    aggregate_edges_kernel<256><<<agg_grid, 256, 0, stream>>>(src, dst, dinv, h, out2);
    bias_act_kernel<256, true><<<ew_grid_256, 256, 0, stream>>>(out2, b2);

    // ---- layer 3 (no activation) ----
    gemm_nt_kernel<<<gemm_grid_o, 256, 0, stream>>>(out2, W3, h, N_NODES, DIM_OUT, DIM_H);
    init_self_kernel<64><<<ew_grid_64, 256, 0, stream>>>(h, dinv, out3);
    aggregate_edges_kernel<64><<<agg_grid, 256, 0, stream>>>(src, dst, dinv, h, out3);
    bias_act_kernel<64, false><<<ew_grid_64, 256, 0, stream>>>(out3, b3);
}

// Round 2
// 851.965 us; speedup vs baseline: 6.9880x; 6.9880x over previous
//
#include <hip/hip_runtime.h>

#define N_NODES 50000
#define E_EDGES 800000
#define DIM_IN 256
#define DIM_H 256
#define DIM_OUT 64
#define SLOPE 0.01f

// ================= CSR build =================

__global__ void zero_counts_kernel(int* __restrict__ counts) {
    int i = blockIdx.x * blockDim.x + threadIdx.x;
    if (i < N_NODES) counts[i] = 0;
}

__global__ void hist_kernel(const int* __restrict__ dst, int* __restrict__ counts) {
    int e = blockIdx.x * blockDim.x + threadIdx.x;
    if (e < E_EDGES) atomicAdd(&counts[dst[e]], 1);
}

// dinv[i] = rsqrt(counts[i] + 1)  (self loop included)
__global__ void dinv_kernel(const int* __restrict__ counts, float* __restrict__ dinv) {
    int i = blockIdx.x * blockDim.x + threadIdx.x;
    if (i < N_NODES) dinv[i] = rsqrtf((float)(counts[i] + 1));
}

// single-block exclusive scan of counts[N] -> row_ptr[N+1]; also copies into cursor
#define SCAN_T 1024
__global__ __launch_bounds__(SCAN_T) void scan_kernel(const int* __restrict__ counts,
                                                      int* __restrict__ row_ptr,
                                                      int* __restrict__ cursor) {
    __shared__ int buf[SCAN_T];
    int tid = threadIdx.x;
    int base = 0;
    for (int c0 = 0; c0 < N_NODES; c0 += SCAN_T) {
        int i = c0 + tid;
        int v = (i < N_NODES) ? counts[i] : 0;
        buf[tid] = v;
        __syncthreads();
        #pragma unroll
        for (int off = 1; off < SCAN_T; off <<= 1) {
            int t = (tid >= off) ? buf[tid - off] : 0;
            __syncthreads();
            buf[tid] += t;
            __syncthreads();
        }
        if (i < N_NODES) {
            int ex = base + buf[tid] - v;
            row_ptr[i] = ex;
            cursor[i] = ex;
        }
        int total = buf[SCAN_T - 1];
        __syncthreads();
        base += total;
    }
    if (tid == 0) row_ptr[N_NODES] = base;
}

__global__ void scatter_kernel(const int* __restrict__ src, const int* __restrict__ dst,
                               int* __restrict__ cursor, int* __restrict__ col_idx) {
    int e = blockIdx.x * blockDim.x + threadIdx.x;
    if (e < E_EDGES) {
        int pos = atomicAdd(&cursor[dst[e]], 1);
        col_idx[pos] = src[e];
    }
}

// ================= GEMM: C[M,Nc] = A[M,K] * B[Nc,K]^T =================

__global__ __launch_bounds__(256) void gemm_nt_kernel(
        const float* __restrict__ A, const float* __restrict__ B,
        float* __restrict__ C, int M, int Nc, int K) {
    const int BM = 64, BN = 64, BK = 32;
    __shared__ float As[BK][BM + 4];
    __shared__ float Bs[BK][BN + 4];

    int bm = blockIdx.x * BM;
    int bn = blockIdx.y * BN;
    int tid = threadIdx.x;
    int tm = (tid >> 4) * 4;
    int tn = (tid & 15) * 4;

    float acc[4][4] = {};

    for (int k0 = 0; k0 < K; k0 += BK) {
        #pragma unroll
        for (int p = 0; p < 2; ++p) {
            int idx = p * 256 + tid;
            int row = idx >> 3;
            int col = (idx & 7) << 2;
            int gr = bm + row;
            float4 v = make_float4(0.f, 0.f, 0.f, 0.f);
            if (gr < M) v = *(const float4*)(A + (size_t)gr * K + k0 + col);
            As[col + 0][row] = v.x; As[col + 1][row] = v.y;
            As[col + 2][row] = v.z; As[col + 3][row] = v.w;
        }
        #pragma unroll
        for (int p = 0; p < 2; ++p) {
            int idx = p * 256 + tid;
            int row = idx >> 3;
            int col = (idx & 7) << 2;
            float4 v = *(const float4*)(B + (size_t)(bn + row) * K + k0 + col);
            Bs[col + 0][row] = v.x; Bs[col + 1][row] = v.y;
            Bs[col + 2][row] = v.z; Bs[col + 3][row] = v.w;
        }
        __syncthreads();

        #pragma unroll
        for (int k = 0; k < BK; ++k) {
            float a[4], b[4];
            #pragma unroll
            for (int i = 0; i < 4; ++i) a[i] = As[k][tm + i];
            #pragma unroll
            for (int j = 0; j < 4; ++j) b[j] = Bs[k][tn + j];
            #pragma unroll
            for (int i = 0; i < 4; ++i)
                #pragma unroll
                for (int j = 0; j < 4; ++j)
                    acc[i][j] = fmaf(a[i], b[j], acc[i][j]);
        }
        __syncthreads();
    }

    #pragma unroll
    for (int i = 0; i < 4; ++i) {
        int row = bm + tm + i;
        if (row < M) {
            float4 v = make_float4(acc[i][0], acc[i][1], acc[i][2], acc[i][3]);
            *(float4*)(C + (size_t)row * Nc + bn + tn) = v;
        }
    }
}

// ================= fused aggregate + self + bias + act =================
// out[d] = act( dinv[d] * ( sum_j dinv[s_j]*h[s_j] + dinv[d]*h[d] ) + b )
// One 64-lane wave per dst node; 4 nodes per 256-thread block.

template<bool ACT>
__global__ __launch_bounds__(256) void agg_fused256_kernel(
        const int* __restrict__ row_ptr, const int* __restrict__ col_idx,
        const float* __restrict__ dinv, const float* __restrict__ h,
        const float* __restrict__ bias, float* __restrict__ out) {
    int node = blockIdx.x * 4 + (threadIdx.x >> 6);
    int lane = threadIdx.x & 63;
    if (node >= N_NODES) return;

    float dd = dinv[node];
    float4 acc = *((const float4*)(h + (size_t)node * 256) + lane);
    acc.x *= dd; acc.y *= dd; acc.z *= dd; acc.w *= dd;   // self term (pre dinv[d] scale)

    int beg = row_ptr[node], end = row_ptr[node + 1];
    for (int j = beg; j < end; ++j) {
        int s = col_idx[j];            // same address across wave -> broadcast
        float ds = dinv[s];
        float4 v = *((const float4*)(h + (size_t)s * 256) + lane);
        acc.x = fmaf(v.x, ds, acc.x);
        acc.y = fmaf(v.y, ds, acc.y);
        acc.z = fmaf(v.z, ds, acc.z);
        acc.w = fmaf(v.w, ds, acc.w);
    }

    const float4 b4 = *((const float4*)bias + lane);
    acc.x = fmaf(acc.x, dd, b4.x);
    acc.y = fmaf(acc.y, dd, b4.y);
    acc.z = fmaf(acc.z, dd, b4.z);
    acc.w = fmaf(acc.w, dd, b4.w);
    if (ACT) {
        acc.x = acc.x > 0.f ? acc.x : SLOPE * acc.x;
        acc.y = acc.y > 0.f ? acc.y : SLOPE * acc.y;
        acc.z = acc.z > 0.f ? acc.z : SLOPE * acc.z;
        acc.w = acc.w > 0.f ? acc.w : SLOPE * acc.w;
    }
    *((float4*)(out + (size_t)node * 256) + lane) = acc;
}

template<bool ACT>
__global__ __launch_bounds__(256) void agg_fused64_kernel(
        const int* __restrict__ row_ptr, const int* __restrict__ col_idx,
        const float* __restrict__ dinv, const float* __restrict__ h,
        const float* __restrict__ bias, float* __restrict__ out) {
    int node = blockIdx.x * 4 + (threadIdx.x >> 6);
    int lane = threadIdx.x & 63;
    if (node >= N_NODES) return;

    float dd = dinv[node];
    float acc = h[(size_t)node * 64 + lane] * dd;

    int beg = row_ptr[node], end = row_ptr[node + 1];
    for (int j = beg; j < end; ++j) {
        int s = col_idx[j];
        acc = fmaf(h[(size_t)s * 64 + lane], dinv[s], acc);
    }

    acc = fmaf(acc, dd, bias[lane]);
    if (ACT) acc = acc > 0.f ? acc : SLOPE * acc;
    out[(size_t)node * 64 + lane] = acc;
}

// ================= launch =================

static inline int cdiv(long long a, long long b) { return (int)((a + b - 1) / b); }

extern "C" void kernel_launch(void* const* d_in, const int* in_sizes, int n_in,
                              void* d_out, int out_size, void* d_ws, size_t ws_size,
                              hipStream_t stream) {
    const float* x  = (const float*)d_in[0];
    const int* ei   = (const int*)d_in[1];
    const float* W1 = (const float*)d_in[2];
    const float* b1 = (const float*)d_in[3];
    const float* W2 = (const float*)d_in[4];
    const float* b2 = (const float*)d_in[5];
    const float* W3 = (const float*)d_in[6];
    const float* b3 = (const float*)d_in[7];

    const int* src = ei;
    const int* dst = ei + E_EDGES;

    // workspace layout (all 256B-aligned regions)
    char* ws = (char*)d_ws;
    int*   counts  = (int*)ws;                         ws += 50048 * 4;   // N ints
    int*   cursor  = (int*)ws;                         ws += 50048 * 4;
    int*   row_ptr = (int*)ws;                         ws += 50048 * 4;   // N+1 ints
    float* dinv    = (float*)ws;                       ws += 50048 * 4;
    int*   col_idx = (int*)ws;                         ws += (size_t)E_EDGES * 4;
    float* h       = (float*)ws;                       // N*256 floats

    float* out1 = (float*)d_out;
    float* out2 = out1 + (size_t)N_NODES * DIM_H;
    float* out3 = out2 + (size_t)N_NODES * DIM_H;

    // ---- CSR build + normalization ----
    zero_counts_kernel<<<cdiv(N_NODES, 256), 256, 0, stream>>>(counts);
    hist_kernel<<<cdiv(E_EDGES, 256), 256, 0, stream>>>(dst, counts);
    dinv_kernel<<<cdiv(N_NODES, 256), 256, 0, stream>>>(counts, dinv);
    scan_kernel<<<1, SCAN_T, 0, stream>>>(counts, row_ptr, cursor);
    scatter_kernel<<<cdiv(E_EDGES, 256), 256, 0, stream>>>(src, dst, cursor, col_idx);

    dim3 gemm_grid_h(cdiv(N_NODES, 64), DIM_H / 64);
    dim3 gemm_grid_o(cdiv(N_NODES, 64), DIM_OUT / 64);
    int agg_grid = cdiv(N_NODES, 4);

    // ---- layer 1 ----
    gemm_nt_kernel<<<gemm_grid_h, 256, 0, stream>>>(x, W1, h, N_NODES, DIM_H, DIM_IN);
    agg_fused256_kernel<true><<<agg_grid, 256, 0, stream>>>(row_ptr, col_idx, dinv, h, b1, out1);

    // ---- layer 2 ----
    gemm_nt_kernel<<<gemm_grid_h, 256, 0, stream>>>(out1, W2, h, N_NODES, DIM_H, DIM_H);
    agg_fused256_kernel<true><<<agg_grid, 256, 0, stream>>>(row_ptr, col_idx, dinv, h, b2, out2);

    // ---- layer 3 (no activation) ----
    gemm_nt_kernel<<<gemm_grid_o, 256, 0, stream>>>(out2, W3, h, N_NODES, DIM_OUT, DIM_H);
    agg_fused64_kernel<false><<<agg_grid, 256, 0, stream>>>(row_ptr, col_idx, dinv, h, b3, out3);
}

// Round 3
// 582.767 us; speedup vs baseline: 10.2160x; 1.4619x over previous
//
#include <hip/hip_runtime.h>

#define N_NODES 50000
#define E_EDGES 800000
#define SLOPE 0.01f

typedef __attribute__((ext_vector_type(8))) short bf16x8;
typedef __attribute__((ext_vector_type(4))) float floatx4;

__device__ __forceinline__ unsigned short f2bf(float f) {
    unsigned u = __builtin_bit_cast(unsigned, f);
    unsigned r = (u + 0x7FFFu + ((u >> 16) & 1u)) >> 16;
    return (unsigned short)r;
}
__device__ __forceinline__ float bf2f(unsigned short h) {
    unsigned u = ((unsigned)h) << 16;
    return __builtin_bit_cast(float, u);
}

// ================= CSR build =================

__global__ void zero_counts_kernel(int* __restrict__ counts) {
    int i = blockIdx.x * blockDim.x + threadIdx.x;
    if (i < N_NODES) counts[i] = 0;
}

__global__ void hist_kernel(const int* __restrict__ dst, int* __restrict__ counts) {
    int e = blockIdx.x * blockDim.x + threadIdx.x;
    if (e < E_EDGES) atomicAdd(&counts[dst[e]], 1);
}

__global__ void dinv_kernel(const int* __restrict__ counts, float* __restrict__ dinv) {
    int i = blockIdx.x * blockDim.x + threadIdx.x;
    if (i < N_NODES) dinv[i] = rsqrtf((float)(counts[i] + 1));
}

// single-block exclusive scan, shuffle-based (3 barriers per 1024-chunk)
#define SCAN_T 1024
__global__ __launch_bounds__(SCAN_T) void scan_kernel(const int* __restrict__ counts,
                                                      int* __restrict__ row_ptr,
                                                      int* __restrict__ cursor) {
    __shared__ int wsum[16];
    int tid = threadIdx.x;
    int lane = tid & 63;
    int wid = tid >> 6;
    int base0 = 0;
    for (int c0 = 0; c0 < N_NODES; c0 += SCAN_T) {
        int i = c0 + tid;
        int v = (i < N_NODES) ? counts[i] : 0;
        int x = v;
        #pragma unroll
        for (int off = 1; off < 64; off <<= 1) {
            int y = __shfl_up(x, off, 64);
            if (lane >= off) x += y;
        }
        if (lane == 63) wsum[wid] = x;
        __syncthreads();
        if (wid == 0) {
            int s = (lane < 16) ? wsum[lane] : 0;
            #pragma unroll
            for (int off = 1; off < 16; off <<= 1) {
                int y = __shfl_up(s, off, 64);
                if (lane >= off) s += y;
            }
            if (lane < 16) wsum[lane] = s;
        }
        __syncthreads();
        int woff = (wid > 0) ? wsum[wid - 1] : 0;
        int total = wsum[15];
        if (i < N_NODES) {
            int ex = base0 + woff + x - v;
            row_ptr[i] = ex;
            cursor[i] = ex;
        }
        base0 += total;
        __syncthreads();
    }
    if (tid == 0) row_ptr[N_NODES] = base0;
}

__global__ void scatter_kernel(const int* __restrict__ src, const int* __restrict__ dst,
                               int* __restrict__ cursor, int* __restrict__ col_idx) {
    int e = blockIdx.x * blockDim.x + threadIdx.x;
    if (e < E_EDGES) {
        int pos = atomicAdd(&cursor[dst[e]], 1);
        col_idx[pos] = src[e];
    }
}

// ================= MFMA GEMM: C[M,N] = A[M,256] * W[N,256]^T, bf16 inputs, bf16 out ====
// W (fp32) staged once to LDS in fragment order; A frags loaded direct from global.
// No barriers in the K-loop. 4 waves per block.

template<int BN, int WAVES_M, int WAVES_N, int MT, int NT, bool AF32>
__global__ __launch_bounds__(256) void gemm_bf16_kernel(
        const void* __restrict__ Av,       // [M,256] bf16 (or fp32 if AF32)
        const float* __restrict__ Wf,      // [N,256] fp32
        unsigned short* __restrict__ C,    // [M,N] bf16
        int M, int Nc) {
    __shared__ unsigned short Bs[BN * 256];

    const int bm = blockIdx.x * (WAVES_M * MT * 16);
    const int bn = blockIdx.y * BN;

    // ---- stage W -> LDS (fragment order), once ----
    for (int c = threadIdx.x; c < BN * 64; c += 256) {
        int n = c >> 6;
        int k = (c & 63) << 2;     // multiple of 4
        float4 v = *(const float4*)(Wf + (size_t)(bn + n) * 256 + k);
        int j = n >> 4, nl = n & 15, kk = k >> 5, kq = (k >> 3) & 3, ke = k & 7;
        int off = (((j * 8 + kk) * 64) + nl * 4 + kq) * 8 + ke;
        ushort4 o;
        o.x = f2bf(v.x); o.y = f2bf(v.y); o.z = f2bf(v.z); o.w = f2bf(v.w);
        *(ushort4*)(Bs + off) = o;
    }
    __syncthreads();

    const int wave = threadIdx.x >> 6;
    const int lane = threadIdx.x & 63;
    const int lm = lane & 15;
    const int q  = lane >> 4;
    const int wm = (wave / WAVES_N) * (MT * 16);
    const int wn = (wave % WAVES_N) * (NT * 16);

    const char* arow[MT];
    #pragma unroll
    for (int i = 0; i < MT; ++i) {
        int r = bm + wm + i * 16 + lm;
        if (r >= M) r = M - 1;                    // clamp; stores are guarded
        arow[i] = (const char*)Av + ((size_t)r * 256 + q * 8) * (AF32 ? 4 : 2);
    }

    floatx4 acc[MT][NT] = {};

    #pragma unroll
    for (int kk = 0; kk < 8; ++kk) {
        bf16x8 a[MT], b[NT];
        #pragma unroll
        for (int i = 0; i < MT; ++i) {
            if (AF32) {
                const float4* p = (const float4*)(arow[i] + kk * 128);
                float4 lo = p[0], hi = p[1];
                bf16x8 t;
                t[0] = (short)f2bf(lo.x); t[1] = (short)f2bf(lo.y);
                t[2] = (short)f2bf(lo.z); t[3] = (short)f2bf(lo.w);
                t[4] = (short)f2bf(hi.x); t[5] = (short)f2bf(hi.y);
                t[6] = (short)f2bf(hi.z); t[7] = (short)f2bf(hi.w);
                a[i] = t;
            } else {
                a[i] = *(const bf16x8*)(arow[i] + kk * 64);
            }
        }
        #pragma unroll
        for (int j = 0; j < NT; ++j) {
            int jt = (wn >> 4) + j;
            b[j] = *(const bf16x8*)(Bs + ((jt * 8 + kk) * 64 + lm * 4 + q) * 8);
        }
        #pragma unroll
        for (int i = 0; i < MT; ++i)
            #pragma unroll
            for (int j = 0; j < NT; ++j)
                acc[i][j] = __builtin_amdgcn_mfma_f32_16x16x32_bf16(a[i], b[j], acc[i][j], 0, 0, 0);
    }

    #pragma unroll
    for (int i = 0; i < MT; ++i) {
        int rb = bm + wm + i * 16 + q * 4;
        #pragma unroll
        for (int r = 0; r < 4; ++r) {
            int row = rb + r;
            if (row < M) {
                #pragma unroll
                for (int j = 0; j < NT; ++j)
                    C[(size_t)row * Nc + bn + wn + j * 16 + lm] = f2bf(acc[i][j][r]);
            }
        }
    }
}

// ================= fused aggregate + self + bias + act (bf16 h, fp32 acc) =============
// out[d] = act( dinv[d]*( sum_j dinv[s_j]*h[s_j] + dinv[d]*h[d] ) + b )

template<bool ACT>
__global__ __launch_bounds__(256) void agg256_kernel(
        const int* __restrict__ row_ptr, const int* __restrict__ col_idx,
        const float* __restrict__ dinv, const unsigned short* __restrict__ hb,
        const float* __restrict__ bias,
        float* __restrict__ out, unsigned short* __restrict__ outb) {
    int node = blockIdx.x * 4 + (threadIdx.x >> 6);
    int lane = threadIdx.x & 63;
    if (node >= N_NODES) return;

    float dd = dinv[node];
    ushort4 sv = *((const ushort4*)(hb + (size_t)node * 256) + lane);
    float ax = bf2f(sv.x) * dd, ay = bf2f(sv.y) * dd;
    float az = bf2f(sv.z) * dd, aw = bf2f(sv.w) * dd;

    int beg = row_ptr[node], end = row_ptr[node + 1];
    int j = beg;
    for (; j + 1 < end; j += 2) {
        int s0 = col_idx[j], s1 = col_idx[j + 1];
        float d0 = dinv[s0], d1 = dinv[s1];
        ushort4 v0 = *((const ushort4*)(hb + (size_t)s0 * 256) + lane);
        ushort4 v1 = *((const ushort4*)(hb + (size_t)s1 * 256) + lane);
        ax = fmaf(bf2f(v0.x), d0, ax); ay = fmaf(bf2f(v0.y), d0, ay);
        az = fmaf(bf2f(v0.z), d0, az); aw = fmaf(bf2f(v0.w), d0, aw);
        ax = fmaf(bf2f(v1.x), d1, ax); ay = fmaf(bf2f(v1.y), d1, ay);
        az = fmaf(bf2f(v1.z), d1, az); aw = fmaf(bf2f(v1.w), d1, aw);
    }
    if (j < end) {
        int s = col_idx[j];
        float ds = dinv[s];
        ushort4 v = *((const ushort4*)(hb + (size_t)s * 256) + lane);
        ax = fmaf(bf2f(v.x), ds, ax); ay = fmaf(bf2f(v.y), ds, ay);
        az = fmaf(bf2f(v.z), ds, az); aw = fmaf(bf2f(v.w), ds, aw);
    }

    const float4 b4 = ((const float4*)bias)[lane];
    ax = fmaf(ax, dd, b4.x); ay = fmaf(ay, dd, b4.y);
    az = fmaf(az, dd, b4.z); aw = fmaf(aw, dd, b4.w);
    if (ACT) {
        ax = ax > 0.f ? ax : SLOPE * ax;
        ay = ay > 0.f ? ay : SLOPE * ay;
        az = az > 0.f ? az : SLOPE * az;
        aw = aw > 0.f ? aw : SLOPE * aw;
    }
    float4 o; o.x = ax; o.y = ay; o.z = az; o.w = aw;
    ((float4*)(out + (size_t)node * 256))[lane] = o;
    ushort4 ob; ob.x = f2bf(ax); ob.y = f2bf(ay); ob.z = f2bf(az); ob.w = f2bf(aw);
    ((ushort4*)(outb + (size_t)node * 256))[lane] = ob;
}

__global__ __launch_bounds__(256) void agg64_kernel(
        const int* __restrict__ row_ptr, const int* __restrict__ col_idx,
        const float* __restrict__ dinv, const unsigned short* __restrict__ hb,
        const float* __restrict__ bias, float* __restrict__ out) {
    int node = blockIdx.x * 4 + (threadIdx.x >> 6);
    int lane = threadIdx.x & 63;
    if (node >= N_NODES) return;

    float dd = dinv[node];
    float acc = bf2f(hb[(size_t)node * 64 + lane]) * dd;

    int beg = row_ptr[node], end = row_ptr[node + 1];
    int j = beg;
    for (; j + 1 < end; j += 2) {
        int s0 = col_idx[j], s1 = col_idx[j + 1];
        float d0 = dinv[s0], d1 = dinv[s1];
        float v0 = bf2f(hb[(size_t)s0 * 64 + lane]);
        float v1 = bf2f(hb[(size_t)s1 * 64 + lane]);
        acc = fmaf(v0, d0, acc);
        acc = fmaf(v1, d1, acc);
    }
    if (j < end) {
        int s = col_idx[j];
        acc = fmaf(bf2f(hb[(size_t)s * 64 + lane]), dinv[s], acc);
    }
    acc = fmaf(acc, dd, bias[lane]);
    out[(size_t)node * 64 + lane] = acc;
}

// ================= launch =================

static inline int cdiv(long long a, long long b) { return (int)((a + b - 1) / b); }

extern "C" void kernel_launch(void* const* d_in, const int* in_sizes, int n_in,
                              void* d_out, int out_size, void* d_ws, size_t ws_size,
                              hipStream_t stream) {
    const float* x  = (const float*)d_in[0];
    const int* ei   = (const int*)d_in[1];
    const float* W1 = (const float*)d_in[2];
    const float* b1 = (const float*)d_in[3];
    const float* W2 = (const float*)d_in[4];
    const float* b2 = (const float*)d_in[5];
    const float* W3 = (const float*)d_in[6];
    const float* b3 = (const float*)d_in[7];

    const int* src = ei;
    const int* dst = ei + E_EDGES;

    char* ws = (char*)d_ws;
    int*   counts  = (int*)ws;  ws += 50048 * 4;
    int*   cursor  = (int*)ws;  ws += 50048 * 4;
    int*   row_ptr = (int*)ws;  ws += 50048 * 4;
    float* dinv    = (float*)ws; ws += 50048 * 4;
    int*   col_idx = (int*)ws;  ws += (size_t)E_EDGES * 4;
    unsigned short* hb = (unsigned short*)ws; ws += (size_t)N_NODES * 256 * 2;  // h (bf16)
    unsigned short* ob = (unsigned short*)ws;                                   // out bf16 copy

    float* out1 = (float*)d_out;
    float* out2 = out1 + (size_t)N_NODES * 256;
    float* out3 = out2 + (size_t)N_NODES * 256;

    // ---- CSR build + normalization ----
    zero_counts_kernel<<<cdiv(N_NODES, 256), 256, 0, stream>>>(counts);
    hist_kernel<<<cdiv(E_EDGES, 256), 256, 0, stream>>>(dst, counts);
    dinv_kernel<<<cdiv(N_NODES, 256), 256, 0, stream>>>(counts, dinv);
    scan_kernel<<<1, SCAN_T, 0, stream>>>(counts, row_ptr, cursor);
    scatter_kernel<<<cdiv(E_EDGES, 256), 256, 0, stream>>>(src, dst, cursor, col_idx);

    dim3 gemm_grid_256(cdiv(N_NODES, 128), 2);
    dim3 gemm_grid_64(cdiv(N_NODES, 128), 1);
    int agg_grid = cdiv(N_NODES, 4);

    // ---- layer 1: GEMM (fp32 A converted in-register) + aggregate ----
    gemm_bf16_kernel<128, 2, 2, 4, 4, true><<<gemm_grid_256, 256, 0, stream>>>(
        x, W1, hb, N_NODES, 256);
    agg256_kernel<true><<<agg_grid, 256, 0, stream>>>(row_ptr, col_idx, dinv, hb, b1, out1, ob);

    // ---- layer 2 ----
    gemm_bf16_kernel<128, 2, 2, 4, 4, false><<<gemm_grid_256, 256, 0, stream>>>(
        ob, W2, hb, N_NODES, 256);
    agg256_kernel<true><<<agg_grid, 256, 0, stream>>>(row_ptr, col_idx, dinv, hb, b2, out2, ob);

    // ---- layer 3 (no activation) ----
    gemm_bf16_kernel<64, 4, 1, 2, 4, false><<<gemm_grid_64, 256, 0, stream>>>(
        ob, W3, hb, N_NODES, 64);
    agg64_kernel<<<agg_grid, 256, 0, stream>>>(row_ptr, col_idx, dinv, hb, b3, out3);
}

// Round 4
// 481.232 us; speedup vs baseline: 12.3715x; 1.2110x over previous
//
#include <hip/hip_runtime.h>

#define N_NODES 50000
#define E_EDGES 800000
#define SLOPE 0.01f

typedef __attribute__((ext_vector_type(8))) short bf16x8;
typedef __attribute__((ext_vector_type(4))) float floatx4;

__device__ __forceinline__ unsigned short f2bf(float f) {
    unsigned u = __builtin_bit_cast(unsigned, f);
    unsigned r = (u + 0x7FFFu + ((u >> 16) & 1u)) >> 16;
    return (unsigned short)r;
}
__device__ __forceinline__ float bf2f(unsigned short h) {
    unsigned u = ((unsigned)h) << 16;
    return __builtin_bit_cast(float, u);
}

// ================= dtype conversion =================

__global__ void f32_to_bf16_kernel(const float* __restrict__ in,
                                   unsigned short* __restrict__ out, int n4) {
    int i = blockIdx.x * blockDim.x + threadIdx.x;
    if (i < n4) {
        float4 v = ((const float4*)in)[i];
        ushort4 o;
        o.x = f2bf(v.x); o.y = f2bf(v.y); o.z = f2bf(v.z); o.w = f2bf(v.w);
        ((ushort4*)out)[i] = o;
    }
}

// W[Nw,256] fp32 -> fragment-ordered bf16:
// ushort addr = ((jt*8+kk)*64 + q*16 + lm)*8 + e,  n=jt*16+lm, k=kk*32+q*8+e
__global__ void wfrag_kernel(const float* __restrict__ Wf,
                             unsigned short* __restrict__ out, int n4) {
    int idx = blockIdx.x * blockDim.x + threadIdx.x;
    if (idx >= n4) return;
    int n = idx >> 6;
    int k = (idx & 63) << 2;
    float4 v = ((const float4*)Wf)[idx];
    int jt = n >> 4, lm = n & 15, kk = k >> 5, q = (k >> 3) & 3, e = k & 7;
    int off = ((jt * 8 + kk) * 64 + q * 16 + lm) * 8 + e;
    ushort4 o;
    o.x = f2bf(v.x); o.y = f2bf(v.y); o.z = f2bf(v.z); o.w = f2bf(v.w);
    *(ushort4*)(out + off) = o;
}

// ================= CSR build =================

__global__ void zero_counts_kernel(int* __restrict__ counts) {
    int i = blockIdx.x * blockDim.x + threadIdx.x;
    if (i < N_NODES) counts[i] = 0;
}

__global__ void hist_kernel(const int* __restrict__ dst, int* __restrict__ counts) {
    int e = blockIdx.x * blockDim.x + threadIdx.x;
    if (e < E_EDGES) atomicAdd(&counts[dst[e]], 1);
}

__global__ void dinv_kernel(const int* __restrict__ counts, float* __restrict__ dinv) {
    int i = blockIdx.x * blockDim.x + threadIdx.x;
    if (i < N_NODES) dinv[i] = rsqrtf((float)(counts[i] + 1));
}

// multiblock exclusive scan: scan1 (per-block) -> scan2 (block sums) -> scan3 (fixup)
#define SB 1024
__global__ __launch_bounds__(SB) void scan1_kernel(const int* __restrict__ counts,
                                                   int* __restrict__ partial,
                                                   int* __restrict__ bsum) {
    __shared__ int wsum[16];
    int tid = threadIdx.x, lane = tid & 63, wid = tid >> 6;
    int i = blockIdx.x * SB + tid;
    int v = (i < N_NODES) ? counts[i] : 0;
    int x = v;
    #pragma unroll
    for (int off = 1; off < 64; off <<= 1) {
        int y = __shfl_up(x, off, 64);
        if (lane >= off) x += y;
    }
    if (lane == 63) wsum[wid] = x;
    __syncthreads();
    if (wid == 0) {
        int s = (lane < 16) ? wsum[lane] : 0;
        #pragma unroll
        for (int off = 1; off < 16; off <<= 1) {
            int y = __shfl_up(s, off, 64);
            if (lane >= off) s += y;
        }
        if (lane < 16) wsum[lane] = s;
    }
    __syncthreads();
    int woff = wid ? wsum[wid - 1] : 0;
    if (i < N_NODES) partial[i] = woff + x - v;
    if (tid == SB - 1) bsum[blockIdx.x] = woff + x;
}

__global__ void scan2_kernel(int* __restrict__ bsum, int nb) {
    int lane = threadIdx.x;
    int v = (lane < nb) ? bsum[lane] : 0;
    #pragma unroll
    for (int off = 1; off < 64; off <<= 1) {
        int y = __shfl_up(v, off, 64);
        if (lane >= off) v += y;
    }
    if (lane < nb) bsum[lane] = v;   // inclusive prefix
}

__global__ void scan3_kernel(int* __restrict__ row_ptr, const int* __restrict__ bsum,
                             int* __restrict__ cursor, int nb) {
    int i = blockIdx.x * blockDim.x + threadIdx.x;
    if (i < N_NODES) {
        int c = i >> 10;
        int off = c ? bsum[c - 1] : 0;
        int ex = row_ptr[i] + off;
        row_ptr[i] = ex;
        cursor[i] = ex;
    }
    if (i == 0) row_ptr[N_NODES] = bsum[nb - 1];
}

__global__ void scatter_kernel(const int* __restrict__ src, const int* __restrict__ dst,
                               int* __restrict__ cursor, int* __restrict__ col_idx) {
    int e = blockIdx.x * blockDim.x + threadIdx.x;
    if (e < E_EDGES) {
        int pos = atomicAdd(&cursor[dst[e]], 1);
        col_idx[pos] = src[e];
    }
}

// ================= LDS-free MFMA GEMM =================
// C[M,Nc] = (A[M,256] @ W^T) * dinv[row]   (bf16 in, bf16 out, fp32 acc)
// B frags pre-laid in global in exact fragment order -> coalesced 1KB loads.
// No LDS, no barriers in K-loop.

template<int WAVES_M, int WAVES_N, int MT, int NT>
__global__ __launch_bounds__(256) void gemm_frag_kernel(
        const unsigned short* __restrict__ Ab,   // [M,256] bf16
        const unsigned short* __restrict__ Bf,   // fragment-ordered bf16
        const float* __restrict__ dinv,
        unsigned short* __restrict__ C, int M, int Nc) {
    const int wave = threadIdx.x >> 6, lane = threadIdx.x & 63;
    const int lm = lane & 15, q = lane >> 4;
    const int bm = blockIdx.x * (WAVES_M * MT * 16);
    const int bn = blockIdx.y * (WAVES_N * NT * 16);
    const int wm = (wave / WAVES_N) * (MT * 16);
    const int wn = (wave % WAVES_N) * (NT * 16);
    const int jt0 = (bn + wn) >> 4;

    const unsigned short* arow[MT];
    #pragma unroll
    for (int i = 0; i < MT; ++i) {
        int r = bm + wm + i * 16 + lm;
        if (r >= M) r = M - 1;                 // clamp; stores guarded
        arow[i] = Ab + (size_t)r * 256 + q * 8;
    }

    floatx4 acc[MT][NT] = {};

    #pragma unroll
    for (int kk = 0; kk < 8; ++kk) {
        bf16x8 a[MT], b[NT];
        #pragma unroll
        for (int i = 0; i < MT; ++i)
            a[i] = *(const bf16x8*)(arow[i] + kk * 32);
        #pragma unroll
        for (int j = 0; j < NT; ++j)
            b[j] = *(const bf16x8*)(Bf + (((jt0 + j) * 8 + kk) * 64 + lane) * 8);
        #pragma unroll
        for (int i = 0; i < MT; ++i)
            #pragma unroll
            for (int j = 0; j < NT; ++j)
                acc[i][j] = __builtin_amdgcn_mfma_f32_16x16x32_bf16(a[i], b[j], acc[i][j], 0, 0, 0);
    }

    #pragma unroll
    for (int i = 0; i < MT; ++i) {
        int rb = bm + wm + i * 16 + q * 4;
        #pragma unroll
        for (int r = 0; r < 4; ++r) {
            int row = rb + r;
            if (row < M) {
                float dd = dinv[row];
                #pragma unroll
                for (int j = 0; j < NT; ++j)
                    C[(size_t)row * Nc + bn + wn + j * 16 + lm] = f2bf(acc[i][j][r] * dd);
            }
        }
    }
}

// ================= fused aggregate (pure gather-sum) =================
// hs rows are pre-scaled by dinv[src] in the GEMM epilogue:
// out[d] = act( dinv[d]*( sum_{s in N(d)} hs[s] + hs[d] ) + b )

template<bool ACT>
__global__ __launch_bounds__(256) void agg256_kernel(
        const int* __restrict__ row_ptr, const int* __restrict__ col_idx,
        const float* __restrict__ dinv, const unsigned short* __restrict__ hs,
        const float* __restrict__ bias,
        float* __restrict__ out, unsigned short* __restrict__ outb) {
    int node = __builtin_amdgcn_readfirstlane(blockIdx.x * 4 + (threadIdx.x >> 6));
    int lane = threadIdx.x & 63;

    float dd = dinv[node];
    ushort4 sv = ((const ushort4*)(hs + (size_t)node * 256))[lane];
    float ax = bf2f(sv.x), ay = bf2f(sv.y), az = bf2f(sv.z), aw = bf2f(sv.w);

    int beg = row_ptr[node], end = row_ptr[node + 1];
    int j = beg;
    for (; j + 3 < end; j += 4) {
        int s0 = col_idx[j], s1 = col_idx[j + 1], s2 = col_idx[j + 2], s3 = col_idx[j + 3];
        ushort4 v0 = ((const ushort4*)(hs + (size_t)s0 * 256))[lane];
        ushort4 v1 = ((const ushort4*)(hs + (size_t)s1 * 256))[lane];
        ushort4 v2 = ((const ushort4*)(hs + (size_t)s2 * 256))[lane];
        ushort4 v3 = ((const ushort4*)(hs + (size_t)s3 * 256))[lane];
        ax += bf2f(v0.x); ay += bf2f(v0.y); az += bf2f(v0.z); aw += bf2f(v0.w);
        ax += bf2f(v1.x); ay += bf2f(v1.y); az += bf2f(v1.z); aw += bf2f(v1.w);
        ax += bf2f(v2.x); ay += bf2f(v2.y); az += bf2f(v2.z); aw += bf2f(v2.w);
        ax += bf2f(v3.x); ay += bf2f(v3.y); az += bf2f(v3.z); aw += bf2f(v3.w);
    }
    for (; j < end; ++j) {
        int s = col_idx[j];
        ushort4 v = ((const ushort4*)(hs + (size_t)s * 256))[lane];
        ax += bf2f(v.x); ay += bf2f(v.y); az += bf2f(v.z); aw += bf2f(v.w);
    }

    const float4 b4 = ((const float4*)bias)[lane];
    ax = fmaf(ax, dd, b4.x); ay = fmaf(ay, dd, b4.y);
    az = fmaf(az, dd, b4.z); aw = fmaf(aw, dd, b4.w);
    if (ACT) {
        ax = ax > 0.f ? ax : SLOPE * ax;
        ay = ay > 0.f ? ay : SLOPE * ay;
        az = az > 0.f ? az : SLOPE * az;
        aw = aw > 0.f ? aw : SLOPE * aw;
    }
    float4 o; o.x = ax; o.y = ay; o.z = az; o.w = aw;
    ((float4*)(out + (size_t)node * 256))[lane] = o;
    ushort4 ob; ob.x = f2bf(ax); ob.y = f2bf(ay); ob.z = f2bf(az); ob.w = f2bf(aw);
    ((ushort4*)(outb + (size_t)node * 256))[lane] = ob;
}

__global__ __launch_bounds__(256) void agg64_kernel(
        const int* __restrict__ row_ptr, const int* __restrict__ col_idx,
        const float* __restrict__ dinv, const unsigned short* __restrict__ hs,
        const float* __restrict__ bias, float* __restrict__ out) {
    int node = __builtin_amdgcn_readfirstlane(blockIdx.x * 4 + (threadIdx.x >> 6));
    int lane = threadIdx.x & 63;

    float dd = dinv[node];
    float acc = bf2f(hs[(size_t)node * 64 + lane]);

    int beg = row_ptr[node], end = row_ptr[node + 1];
    int j = beg;
    for (; j + 3 < end; j += 4) {
        int s0 = col_idx[j], s1 = col_idx[j + 1], s2 = col_idx[j + 2], s3 = col_idx[j + 3];
        acc += bf2f(hs[(size_t)s0 * 64 + lane]);
        acc += bf2f(hs[(size_t)s1 * 64 + lane]);
        acc += bf2f(hs[(size_t)s2 * 64 + lane]);
        acc += bf2f(hs[(size_t)s3 * 64 + lane]);
    }
    for (; j < end; ++j)
        acc += bf2f(hs[(size_t)col_idx[j] * 64 + lane]);

    acc = fmaf(acc, dd, bias[lane]);
    out[(size_t)node * 64 + lane] = acc;
}

// ================= launch =================

static inline int cdiv(long long a, long long b) { return (int)((a + b - 1) / b); }

extern "C" void kernel_launch(void* const* d_in, const int* in_sizes, int n_in,
                              void* d_out, int out_size, void* d_ws, size_t ws_size,
                              hipStream_t stream) {
    const float* x  = (const float*)d_in[0];
    const int* ei   = (const int*)d_in[1];
    const float* W1 = (const float*)d_in[2];
    const float* b1 = (const float*)d_in[3];
    const float* W2 = (const float*)d_in[4];
    const float* b2 = (const float*)d_in[5];
    const float* W3 = (const float*)d_in[6];
    const float* b3 = (const float*)d_in[7];

    const int* src = ei;
    const int* dst = ei + E_EDGES;

    char* ws = (char*)d_ws;
    int*   counts  = (int*)ws;   ws += 50048 * 4;
    int*   cursor  = (int*)ws;   ws += 50048 * 4;
    int*   row_ptr = (int*)ws;   ws += 50112 * 4;   // N+1
    float* dinv    = (float*)ws; ws += 50048 * 4;
    int*   bsum    = (int*)ws;   ws += 64 * 4;
    int*   col_idx = (int*)ws;   ws += (size_t)E_EDGES * 4;
    unsigned short* W1f = (unsigned short*)ws; ws += 65536 * 2;
    unsigned short* W2f = (unsigned short*)ws; ws += 65536 * 2;
    unsigned short* W3f = (unsigned short*)ws; ws += 16384 * 2;
    unsigned short* hb  = (unsigned short*)ws; ws += (size_t)N_NODES * 256 * 2;  // hs (prescaled)
    unsigned short* ob  = (unsigned short*)ws;                                   // bf16 activations

    float* out1 = (float*)d_out;
    float* out2 = out1 + (size_t)N_NODES * 256;
    float* out3 = out2 + (size_t)N_NODES * 256;

    const int NB = cdiv(N_NODES, SB);   // 49

    // ---- conversions ----
    f32_to_bf16_kernel<<<cdiv((long long)N_NODES * 256 / 4, 256), 256, 0, stream>>>(
        x, ob, N_NODES * 256 / 4);
    wfrag_kernel<<<cdiv(256 * 64, 256), 256, 0, stream>>>(W1, W1f, 256 * 64);
    wfrag_kernel<<<cdiv(256 * 64, 256), 256, 0, stream>>>(W2, W2f, 256 * 64);
    wfrag_kernel<<<cdiv(64 * 64, 256), 256, 0, stream>>>(W3, W3f, 64 * 64);

    // ---- CSR build + normalization ----
    zero_counts_kernel<<<cdiv(N_NODES, 256), 256, 0, stream>>>(counts);
    hist_kernel<<<cdiv(E_EDGES, 256), 256, 0, stream>>>(dst, counts);
    dinv_kernel<<<cdiv(N_NODES, 256), 256, 0, stream>>>(counts, dinv);
    scan1_kernel<<<NB, SB, 0, stream>>>(counts, row_ptr, bsum);
    scan2_kernel<<<1, 64, 0, stream>>>(bsum, NB);
    scan3_kernel<<<cdiv(N_NODES, 256), 256, 0, stream>>>(row_ptr, bsum, cursor, NB);
    scatter_kernel<<<cdiv(E_EDGES, 256), 256, 0, stream>>>(src, dst, cursor, col_idx);

    dim3 g256(cdiv(N_NODES, 128), 2);   // 128x128 blocks
    dim3 g64(cdiv(N_NODES, 256), 1);    // 256x64 blocks
    int agg_grid = cdiv(N_NODES, 4);

    // ---- layer 1 ----
    gemm_frag_kernel<2, 2, 4, 4><<<g256, 256, 0, stream>>>(ob, W1f, dinv, hb, N_NODES, 256);
    agg256_kernel<true><<<agg_grid, 256, 0, stream>>>(row_ptr, col_idx, dinv, hb, b1, out1, ob);

    // ---- layer 2 ----
    gemm_frag_kernel<2, 2, 4, 4><<<g256, 256, 0, stream>>>(ob, W2f, dinv, hb, N_NODES, 256);
    agg256_kernel<true><<<agg_grid, 256, 0, stream>>>(row_ptr, col_idx, dinv, hb, b2, out2, ob);

    // ---- layer 3 (no activation) ----
    gemm_frag_kernel<4, 1, 4, 4><<<g64, 256, 0, stream>>>(ob, W3f, dinv, hb, N_NODES, 64);
    agg64_kernel<<<agg_grid, 256, 0, stream>>>(row_ptr, col_idx, dinv, hb, b3, out3);
}